// Round 1
// baseline (210.191 us; speedup 1.0000x reference)
//
#include <hip/hip_runtime.h>
#include <hip/hip_bf16.h>

#define SEQ 41
#define FEAT 128
#define KDIM 384          // 3 * 128
#define BM 64
#define BK 64
#define LDA (BK + 8)      // padded LDS stride (bf16 elems): 144 B rows -> 2-way max
#define LDB (BK + 8)

typedef float floatx4 __attribute__((ext_vector_type(4)));
typedef __bf16 bf16x8 __attribute__((ext_vector_type(8)));
typedef unsigned short ushortx8 __attribute__((ext_vector_type(8)));

// fp32 -> bf16 bits, round-to-nearest-even (inputs are finite normals)
__device__ __forceinline__ unsigned short f2bf(float f) {
    unsigned int u = __builtin_bit_cast(unsigned int, f);
    unsigned int r = (u + 0x7fffu + ((u >> 16) & 1u)) >> 16;
    return (unsigned short)r;
}

// ---------------- prepass: W (s, k, n) fp32 -> Wt (s, n, k) bf16 ----------------
__global__ __launch_bounds__(256) void wt_kernel(const float* __restrict__ W,
                                                 unsigned short* __restrict__ Wt) {
    int t = blockIdx.x * 256 + threadIdx.x;           // 41*128*48 = 251904 total
    int n  = t & (FEAT - 1);
    int r  = t >> 7;
    int k0 = (r % (KDIM / 8)) * 8;
    int s  = r / (KDIM / 8);
    const float* Ws = W + (size_t)s * KDIM * FEAT;
    ushortx8 v;
#pragma unroll
    for (int j = 0; j < 8; j++) v[j] = f2bf(Ws[(size_t)(k0 + j) * FEAT + n]);
    *reinterpret_cast<ushortx8*>(Wt + ((size_t)(s * FEAT + n)) * KDIM + k0) = v;
}

// ---------------- main GEMM: per (s, m-tile), C = relu(X_s * W_s + b_s) --------
// USE_WT=1: Wsrc is pre-transposed bf16 Wt[s][n][k]. USE_WT=0: Wsrc is fp32 W[s][k][n].
template <int USE_WT>
__global__ __launch_bounds__(256) void gemm_kernel(const float* __restrict__ X,
                                                   const void* __restrict__ Wsrc,
                                                   const float* __restrict__ bias,
                                                   float* __restrict__ out) {
    __shared__ unsigned short Alds[BM][LDA];
    __shared__ unsigned short Blds[FEAT][LDB];

    const int tid = threadIdx.x;
    const int s   = blockIdx.y;
    const int m0  = blockIdx.x * BM;

    const int lane = tid & 63;
    const int wv   = tid >> 6;
    const int colq = lane & 15;
    const int quad = lane >> 4;
    const int arow = 16 * wv + colq;

    floatx4 acc[8];
#pragma unroll
    for (int nt = 0; nt < 8; nt++) acc[nt] = (floatx4){0.f, 0.f, 0.f, 0.f};

    // A-staging mapping (fixed across K iters)
    const int a_row = tid & 63;
    const int a_seg = tid >> 6;                       // 0..3, 16 floats each
    const float* xrow = X + (size_t)(m0 + a_row) * (SEQ * FEAT);

    for (int kk = 0; kk < KDIM; kk += BK) {
        // ---- stage A: 64 rows x 64 cols, fp32 -> bf16, bounds = zero padding
        {
            int kbase = kk + a_seg * 16;
            int toff  = (s - 1) * FEAT + kbase;       // offset within this batch row
            ushortx8 lo, hi;
#pragma unroll
            for (int j = 0; j < 4; j++) {
                int o = toff + j * 4;
                floatx4 v = (floatx4){0.f, 0.f, 0.f, 0.f};
                if (o >= 0 && o < SEQ * FEAT)
                    v = *reinterpret_cast<const floatx4*>(xrow + o);
#pragma unroll
                for (int e = 0; e < 4; e++) {
                    unsigned short b = f2bf(v[e]);
                    if (j < 2) lo[j * 4 + e] = b; else hi[(j - 2) * 4 + e] = b;
                }
            }
            *reinterpret_cast<ushortx8*>(&Alds[a_row][a_seg * 16])     = lo;
            *reinterpret_cast<ushortx8*>(&Alds[a_row][a_seg * 16 + 8]) = hi;
        }
        // ---- stage B: 128 n-rows x 64 k-cols (n-major in LDS)
        if (USE_WT) {
            const unsigned short* Wt = (const unsigned short*)Wsrc;
#pragma unroll
            for (int i = 0; i < 4; i++) {
                int chunk = i * 256 + tid;            // 0..1023
                int n  = chunk >> 3;
                int c8 = (chunk & 7) << 3;
                ushortx8 v = *reinterpret_cast<const ushortx8*>(
                    Wt + ((size_t)(s * FEAT + n)) * KDIM + kk + c8);
                *reinterpret_cast<ushortx8*>(&Blds[n][c8]) = v;
            }
        } else {
            const float* Wf = (const float*)Wsrc;
#pragma unroll
            for (int i = 0; i < 8; i++) {
                int q  = i * 256 + tid;               // 0..2047
                int n4 = (q & 31) * 4;
                int c  = q >> 5;                      // 0..63
                floatx4 v = *reinterpret_cast<const floatx4*>(
                    Wf + ((size_t)(s * KDIM) + kk + c) * FEAT + n4);
#pragma unroll
                for (int j = 0; j < 4; j++) Blds[n4 + j][c] = f2bf(v[j]);
            }
        }
        __syncthreads();

        // ---- compute: 2 k-steps of 32, 8 n-tiles
#pragma unroll
        for (int ks = 0; ks < 2; ks++) {
            bf16x8 av = *reinterpret_cast<const bf16x8*>(&Alds[arow][ks * 32 + quad * 8]);
#pragma unroll
            for (int nt = 0; nt < 8; nt++) {
                bf16x8 bv = *reinterpret_cast<const bf16x8*>(
                    &Blds[nt * 16 + colq][ks * 32 + quad * 8]);
                acc[nt] = __builtin_amdgcn_mfma_f32_16x16x32_bf16(av, bv, acc[nt], 0, 0, 0);
            }
        }
        __syncthreads();
    }

    // ---- epilogue: bias + relu, scalar stores (64 B segments per quad)
    const int m_base = m0 + 16 * wv + quad * 4;
#pragma unroll
    for (int nt = 0; nt < 8; nt++) {
        int n = nt * 16 + colq;
        float bv = bias[s * FEAT + n];
#pragma unroll
        for (int r = 0; r < 4; r++) {
            float v = acc[nt][r] + bv;
            v = v > 0.f ? v : 0.f;
            out[((size_t)(m_base + r) * SEQ + s) * FEAT + n] = v;
        }
    }
}

extern "C" void kernel_launch(void* const* d_in, const int* in_sizes, int n_in,
                              void* d_out, int out_size, void* d_ws, size_t ws_size,
                              hipStream_t stream) {
    const float* X    = (const float*)d_in[0];
    const float* W    = (const float*)d_in[1];
    const float* bias = (const float*)d_in[2];
    float* out = (float*)d_out;

    const int B = in_sizes[0] / (SEQ * FEAT);         // 4096
    dim3 grid(B / BM, SEQ);

    const size_t wt_bytes = (size_t)SEQ * FEAT * KDIM * sizeof(unsigned short);
    if (ws_size >= wt_bytes) {
        unsigned short* Wt = (unsigned short*)d_ws;
        wt_kernel<<<(SEQ * FEAT * (KDIM / 8) + 255) / 256, 256, 0, stream>>>(W, Wt);
        gemm_kernel<1><<<grid, 256, 0, stream>>>(X, (const void*)Wt, bias, out);
    } else {
        gemm_kernel<0><<<grid, 256, 0, stream>>>(X, (const void*)W, bias, out);
    }
}